// Round 5
// baseline (326.575 us; speedup 1.0000x reference)
//
#include <hip/hip_runtime.h>
#include <hip/hip_bf16.h>
#include <hip/hip_fp16.h>

#define B_ 32
#define T_ 2048
#define D_ 1024
#define U_ 1024
#define M_ (B_ * T_)   // 65536
#define NT_ 4          // U_/256 partial-logit slabs

typedef _Float16 f16x8 __attribute__((ext_vector_type(8)));
typedef float f32x4 __attribute__((ext_vector_type(4)));

__device__ __forceinline__ float fast_tanh(float x) {
    float xc = fminf(fmaxf(x, -10.f), 10.f);
    float e = __expf(2.f * xc);
    return 1.f - 2.f / (e + 1.f);
}

__device__ __forceinline__ void load_lds16(const void* g, void* l) {
    __builtin_amdgcn_global_load_lds(
        (const __attribute__((address_space(1))) void*)g,
        (__attribute__((address_space(3))) void*)l, 16, 0, 0);
}

// ---------------- W1 [D][U] f32 -> W1t [U][D] f16 ----------------
__global__ void transpose_cast_kernel(const float* __restrict__ W1,
                                      _Float16* __restrict__ W1t) {
    int u = blockIdx.x * 256 + threadIdx.x;   // grid.x = 4
    int d0 = blockIdx.y * 64;                 // grid.y = 16
    for (int j8 = 0; j8 < 8; ++j8) {
        f16x8 h;
        #pragma unroll
        for (int j = 0; j < 8; ++j)
            h[j] = (_Float16)W1[(size_t)(d0 + j8 * 8 + j) * U_ + u];
        *(f16x8*)&W1t[(size_t)u * D_ + d0 + j8 * 8] = h;
    }
}

// ---------------- proj_h ----------------
__global__ void proj_h_partial_kernel(const float* __restrict__ hidden,
                                      const float* __restrict__ W2,
                                      float* __restrict__ pph) {
    int u = blockIdx.x * 256 + threadIdx.x;   // grid.x = 4
    int c = blockIdx.y;                       // grid.y = 8
    __shared__ float hb[32][128];
    for (int i = threadIdx.x; i < 32 * 128; i += 256)
        hb[i >> 7][i & 127] = hidden[(i >> 7) * D_ + c * 128 + (i & 127)];
    __syncthreads();
    float acc[32] = {};
    for (int d = 0; d < 128; ++d) {
        float w = W2[(size_t)(c * 128 + d) * U_ + u];
        #pragma unroll
        for (int b = 0; b < 32; ++b) acc[b] = fmaf(hb[b][d], w, acc[b]);
    }
    #pragma unroll
    for (int b = 0; b < 32; ++b)
        pph[((size_t)c * 32 + b) * U_ + u] = acc[b];
}

__global__ void proj_h_combine_kernel(const float* __restrict__ pph,
                                      const float* __restrict__ b1,
                                      const float* __restrict__ b2,
                                      float* __restrict__ ph) {
    int u = blockIdx.x * 256 + threadIdx.x;
    float bias = b1[u] + b2[u];
    for (int b = 0; b < 32; ++b) {
        float s = bias;
        #pragma unroll
        for (int c = 0; c < 8; ++c) s += pph[((size_t)c * 32 + b) * U_ + u];
        ph[b * U_ + u] = s;
    }
}

// ============ fused 256x256 fine-phase GEMM + tanh + dot(V) ============
// BM=BN=256, BK=64 (2 khalves), 512 thr = 8 waves (2M x 4N), wave tile 128x64.
// LDS 128KB: bufA{0,1} @0/32K, bufB{0,1} @64K/96K, each 256 rows x 128B.
// 8-unit XOR swizzle (phys_unit = logical ^ (row&7)), both sides.
// A: f32 HBM -> regs (issue ph1) -> cvt f16 -> swizzled ds_write (ph4).
// B: f16 via global_load_lds (issue ph1), linear dest + inv-swizzled source.
// 4 phases per K-tile, barrier pair per phase, one vmcnt(0) per tile (ph4).

#define SB0 __builtin_amdgcn_sched_barrier(0);
#define BAR __builtin_amdgcn_s_barrier();
#define LGKM0 asm volatile("s_waitcnt lgkmcnt(0)" ::: "memory");
#define VM0 asm volatile("s_waitcnt vmcnt(0)" ::: "memory");

#define ISSUE_A(koff) do { \
    const float* a0_ = pA0 + (koff); \
    const float* a1_ = pA1 + (koff); \
    araw0 = *(const f32x4*)(a0_);      araw1 = *(const f32x4*)(a0_ + 4); \
    araw2 = *(const f32x4*)(a0_ + 8);  araw3 = *(const f32x4*)(a0_ + 12); \
    araw4 = *(const f32x4*)(a1_);      araw5 = *(const f32x4*)(a1_ + 4); \
    araw6 = *(const f32x4*)(a1_ + 8);  araw7 = *(const f32x4*)(a1_ + 12); \
} while (0)

#define ISSUE_B(koffb, bufoff) do { \
    load_lds16(pB + 0 * 131072 + (koffb), smem + (bufoff) + 0 * 8192 + tid * 16); \
    load_lds16(pB + 1 * 131072 + (koffb), smem + (bufoff) + 1 * 8192 + tid * 16); \
    load_lds16(pB + 2 * 131072 + (koffb), smem + (bufoff) + 2 * 8192 + tid * 16); \
    load_lds16(pB + 3 * 131072 + (koffb), smem + (bufoff) + 3 * 8192 + tid * 16); \
} while (0)

#define WRITE_A(nbptr) do { \
    f16x8 h0_, h1_, h2_, h3_; \
    h0_[0]=(_Float16)araw0[0]; h0_[1]=(_Float16)araw0[1]; h0_[2]=(_Float16)araw0[2]; h0_[3]=(_Float16)araw0[3]; \
    h0_[4]=(_Float16)araw1[0]; h0_[5]=(_Float16)araw1[1]; h0_[6]=(_Float16)araw1[2]; h0_[7]=(_Float16)araw1[3]; \
    h1_[0]=(_Float16)araw2[0]; h1_[1]=(_Float16)araw2[1]; h1_[2]=(_Float16)araw2[2]; h1_[3]=(_Float16)araw2[3]; \
    h1_[4]=(_Float16)araw3[0]; h1_[5]=(_Float16)araw3[1]; h1_[6]=(_Float16)araw3[2]; h1_[7]=(_Float16)araw3[3]; \
    h2_[0]=(_Float16)araw4[0]; h2_[1]=(_Float16)araw4[1]; h2_[2]=(_Float16)araw4[2]; h2_[3]=(_Float16)araw4[3]; \
    h2_[4]=(_Float16)araw5[0]; h2_[5]=(_Float16)araw5[1]; h2_[6]=(_Float16)araw5[2]; h2_[7]=(_Float16)araw5[3]; \
    h3_[0]=(_Float16)araw6[0]; h3_[1]=(_Float16)araw6[1]; h3_[2]=(_Float16)araw6[2]; h3_[3]=(_Float16)araw6[3]; \
    h3_[4]=(_Float16)araw7[0]; h3_[5]=(_Float16)araw7[1]; h3_[6]=(_Float16)araw7[2]; h3_[7]=(_Float16)araw7[3]; \
    *(f16x8*)((nbptr) + aw00) = h0_; \
    *(f16x8*)((nbptr) + aw01) = h1_; \
    *(f16x8*)((nbptr) + aw10) = h2_; \
    *(f16x8*)((nbptr) + aw11) = h3_; \
} while (0)

#define MFMA16(mh) do { \
    _Pragma("unroll") \
    for (int m_ = 0; m_ < 4; ++m_) { \
        _Pragma("unroll") \
        for (int n_ = 0; n_ < 4; ++n_) \
            acc[(mh) * 4 + m_][n_] = __builtin_amdgcn_mfma_f32_16x16x32_f16( \
                af[m_], bf[n_], acc[(mh) * 4 + m_][n_], 0, 0, 0); \
    } \
} while (0)

#define READ_AF(kh, mh) do { \
    int us_ = ((((kh) << 2) | lksl) ^ sw7) << 4; \
    _Pragma("unroll") \
    for (int m_ = 0; m_ < 4; ++m_) \
        af[m_] = *(const f16x8*)(cbA + rowA + ((mh) * 4 + m_) * 2048 + us_); \
} while (0)

#define READ_BF(kh) do { \
    int us_ = ((((kh) << 2) | lksl) ^ sw7) << 4; \
    _Pragma("unroll") \
    for (int n_ = 0; n_ < 4; ++n_) \
        bf[n_] = *(const f16x8*)(cbB + rowB + n_ * 2048 + us_); \
} while (0)

#define PHASE_SYNC(mh) do { \
    SB0 BAR LGKM0 SB0 \
    __builtin_amdgcn_s_setprio(1); \
    MFMA16(mh); \
    __builtin_amdgcn_s_setprio(0); \
    SB0 BAR SB0 \
} while (0)

__global__ __launch_bounds__(512, 1)
void gemm_logits_v5_kernel(const float* __restrict__ A,      // features [M][D] f32
                           const _Float16* __restrict__ Bt,  // W1t [U][D] f16
                           const float* __restrict__ ph,
                           const float* __restrict__ V,
                           float* __restrict__ part)         // [NT_][M]
{
    __shared__ __align__(16) char smem[131072];

    int bid = blockIdx.x;
    int xcd = bid & 7, local = bid >> 3;
    int mt = xcd * 32 + (local >> 2);   // 0..255
    int nt = local & 3;                 // 0..3

    int tid = threadIdx.x;
    int l = tid & 63, wid = tid >> 6;
    int wr = wid >> 2, wc = wid & 3;    // 2M x 4N waves
    int lrow = l & 15, lksl = l >> 4;   // 0..3
    int sw7 = lrow & 7;

    const float* Ag = A + (size_t)mt * 256 * D_;
    const _Float16* Bg = Bt + (size_t)nt * 256 * D_;

    // A staging: rows (tid>>2) and (tid>>2)+128, 16 f32 each
    const float* pA0 = Ag + (size_t)(tid >> 2) * D_ + (tid & 3) * 16;
    const float* pA1 = pA0 + (size_t)128 * D_;
    int c2 = (tid & 3) * 2;
    int r0 = tid >> 2;
    int sw = r0 & 7;
    int aw00 = r0 * 128 + ((c2 ^ sw) << 4);
    int aw01 = r0 * 128 + (((c2 | 1) ^ sw) << 4);
    int aw10 = (r0 + 128) * 128 + ((c2 ^ sw) << 4);
    int aw11 = (r0 + 128) * 128 + (((c2 | 1) ^ sw) << 4);

    // B staging: linear dest, inverse-swizzled source
    int bchunk = (tid & 7) ^ ((tid >> 3) & 7);
    const char* pB = (const char*)Bg + (size_t)(tid >> 3) * 2048 + bchunk * 16;

    // ds_read bases (byte offsets within a buffer)
    int rowA = (wr * 128 + lrow) * 128;
    int rowB = (wc * 64 + lrow) * 128;

    f32x4 acc[8][4] = {};
    f32x4 araw0, araw1, araw2, araw3, araw4, araw5, araw6, araw7;
    f16x8 af[4], bf[4];

    // ---- prologue: stage tile 0 ----
    ISSUE_B(0, 65536);      // bufB0
    ISSUE_A(0);
    SB0 VM0 SB0
    WRITE_A(smem);          // bufA0
    LGKM0 SB0
    BAR SB0

    #pragma unroll 1
    for (int t = 0; t < 16; ++t) {
        const char* cbA = smem + (t & 1) * 32768;
        const char* cbB = smem + 65536 + (t & 1) * 32768;
        char* nbA = smem + ((t & 1) ^ 1) * 32768;
        int nbB = 65536 + (((t & 1) ^ 1)) * 32768;
        bool pf = (t < 15);

        // phase 1: kh=0, mh=0 — read bf0+af, issue next-tile A and B
        READ_BF(0);
        READ_AF(0, 0);
        if (pf) {
            ISSUE_B((t + 1) * 128, nbB);
            ISSUE_A((t + 1) * 64);
        }
        PHASE_SYNC(0);

        // phase 2: kh=0, mh=1
        READ_AF(0, 1);
        PHASE_SYNC(1);

        // phase 3: kh=1, mh=0
        READ_BF(1);
        READ_AF(1, 0);
        PHASE_SYNC(0);

        // phase 4: kh=1, mh=1 — drain vmem, write next A tile
        READ_AF(1, 1);
        if (pf) {
            SB0 VM0 SB0
            WRITE_A(nbA);
        }
        PHASE_SYNC(1);
    }

    // ---- fused epilogue: s = tanh(acc + ph), partial = sum_u s*V ----
    int bidx = mt >> 3;
    const float* phb = ph + bidx * U_;
    float Vv[4], phv[4];
    #pragma unroll
    for (int n = 0; n < 4; ++n) {
        int u = nt * 256 + wc * 64 + n * 16 + lrow;
        Vv[n] = V[u];
        phv[n] = phb[u];
    }
    float* lbuf = (float*)smem;   // bufA0 region; tile15 read bufA1/bufB1 -> disjoint
    #pragma unroll
    for (int m = 0; m < 8; ++m) {
        #pragma unroll
        for (int r = 0; r < 4; ++r) {
            float p = 0.f;
            #pragma unroll
            for (int n = 0; n < 4; ++n) {
                float s = fast_tanh(acc[m][n][r] + phv[n]);
                p = fmaf(s, Vv[n], p);
            }
            #pragma unroll
            for (int off = 1; off < 16; off <<= 1)
                p += __shfl_xor(p, off, 64);
            if (lrow == 0) {
                int row = wr * 128 + m * 16 + ((l >> 4) << 2) + r;
                lbuf[wc * 256 + row] = p;
            }
        }
    }
    __syncthreads();
    if (tid < 256) {
        float v = lbuf[tid] + lbuf[256 + tid] + lbuf[512 + tid] + lbuf[768 + tid];
        part[(size_t)nt * M_ + mt * 256 + tid] = v;
    }
}

// ---------------- softmax over T per batch ----------------
__global__ void softmax_kernel(const float* __restrict__ part,
                               float* __restrict__ wout) {
    int b = blockIdx.x;
    int tid = threadIdx.x;
    __shared__ float red[8];
    float lg[8];
    #pragma unroll
    for (int j = 0; j < 8; ++j) {
        int t = tid + j * 256;
        float s = 0.f;
        #pragma unroll
        for (int p = 0; p < NT_; ++p)
            s += part[(size_t)p * M_ + b * T_ + t];
        lg[j] = s;
    }
    float mx = lg[0];
    #pragma unroll
    for (int j = 1; j < 8; ++j) mx = fmaxf(mx, lg[j]);
    #pragma unroll
    for (int off = 1; off < 64; off <<= 1) mx = fmaxf(mx, __shfl_xor(mx, off, 64));
    int wv = tid >> 6;
    if ((tid & 63) == 0) red[wv] = mx;
    __syncthreads();
    mx = fmaxf(fmaxf(red[0], red[1]), fmaxf(red[2], red[3]));
    float e[8];
    float sum = 0.f;
    #pragma unroll
    for (int j = 0; j < 8; ++j) { e[j] = __expf(lg[j] - mx); sum += e[j]; }
    #pragma unroll
    for (int off = 1; off < 64; off <<= 1) sum += __shfl_xor(sum, off, 64);
    if ((tid & 63) == 0) red[4 + wv] = sum;
    __syncthreads();
    sum = red[4] + red[5] + red[6] + red[7];
    float inv = 1.f / sum;
    #pragma unroll
    for (int j = 0; j < 8; ++j)
        wout[b * T_ + tid + j * 256] = e[j] * inv;
}

// ---------------- context = sum_t w_t * features[b,t,:] (f32) ----------------
#define TCH 128
__global__ void context_partial_kernel(const float* __restrict__ feats,
                                       const float* __restrict__ w,
                                       float* __restrict__ cpart) {
    int b = blockIdx.x, tc = blockIdx.y, tid = threadIdx.x;
    f32x4 acc = {0.f, 0.f, 0.f, 0.f};
    const float* f = feats + ((size_t)b * T_ + tc * TCH) * D_ + tid * 4;
    const float* wp = w + b * T_ + tc * TCH;
    for (int t = 0; t < TCH; ++t) {
        float wt = wp[t];
        f32x4 fv = *(const f32x4*)(f + (size_t)t * D_);
        acc[0] = fmaf(wt, fv[0], acc[0]);
        acc[1] = fmaf(wt, fv[1], acc[1]);
        acc[2] = fmaf(wt, fv[2], acc[2]);
        acc[3] = fmaf(wt, fv[3], acc[3]);
    }
    *(f32x4*)&cpart[((size_t)tc * B_ + b) * D_ + tid * 4] = acc;
}

__global__ void context_reduce_kernel(const float* __restrict__ cpart,
                                      float* __restrict__ out) {
    int i = blockIdx.x * 256 + threadIdx.x;
    float s = 0.f;
    #pragma unroll
    for (int tc = 0; tc < 16; ++tc)
        s += cpart[(size_t)tc * (B_ * D_) + i];
    out[i] = s;
}

extern "C" void kernel_launch(void* const* d_in, const int* in_sizes, int n_in,
                              void* d_out, int out_size, void* d_ws, size_t ws_size,
                              hipStream_t stream) {
    const float* features = (const float*)d_in[0];
    const float* hidden   = (const float*)d_in[1];
    const float* W1       = (const float*)d_in[2];
    const float* b1       = (const float*)d_in[3];
    const float* W2       = (const float*)d_in[4];
    const float* b2       = (const float*)d_in[5];
    const float* V        = (const float*)d_in[6];
    // bV drops out of softmax (shift-invariant).

    float* ctx_out = (float*)d_out;            // [B,D]
    float* w_out   = ctx_out + B_ * D_;        // [B,T,1]

    char* ws = (char*)d_ws;
    _Float16* W1t = (_Float16*)ws;                      // 2 MB @ 0
    float* ph     = (float*)(ws + (size_t)(2 << 20));   // 128 KB @ 2M
    float* pph    = (float*)(ws + (size_t)(3 << 20));   // 1 MB @ 3M
    float* part   = (float*)(ws + (size_t)(4 << 20));   // 1 MB @ 4M
    float* cpart  = (float*)(ws + (size_t)(6 << 20));   // 2 MB @ 6M

    transpose_cast_kernel<<<dim3(4, 16), 256, 0, stream>>>(W1, W1t);
    proj_h_partial_kernel<<<dim3(4, 8), 256, 0, stream>>>(hidden, W2, pph);
    proj_h_combine_kernel<<<4, 256, 0, stream>>>(pph, b1, b2, ph);

    gemm_logits_v5_kernel<<<(M_ / 256) * (U_ / 256), 512, 0, stream>>>(
        features, W1t, ph, V, part);

    softmax_kernel<<<B_, 256, 0, stream>>>(part, w_out);
    context_partial_kernel<<<dim3(B_, 16), 256, 0, stream>>>(features, w_out, cpart);
    context_reduce_kernel<<<(B_ * D_) / 256, 256, 0, stream>>>(cpart, ctx_out);
}